// Round 10
// baseline (118.932 us; speedup 1.0000x reference)
//
#include <hip/hip_runtime.h>
#include <hip/hip_bf16.h>

#define BB 8
#define NN 2048
#define DD 128
#define TI 16     // i-rows per block (hw GEMM)
#define HP 132    // padded row stride for 128-wide LDS tiles
#define CH 32     // scan chunk length (sorted rows per scan block)
#define NC (NN / CH)          // 64 chunks per batch
#define NO (NC + 1)           // 65 offset rows (incl. grand total)

__device__ __forceinline__ float relu(float x) { return x > 0.f ? x : 0.f; }

// ---------- Kernel 0: WT[d][e] = W[e][d] ----------
__global__ __launch_bounds__(256) void GraphAttentionalLayer_1168231104632_tr(
    const float* __restrict__ W, float* __restrict__ WT)
{
    const int g = blockIdx.x * 256 + threadIdx.x;   // g = d*128 + e
    const int d = g >> 7, e = g & 127;
    WT[g] = W[e * DD + d];
}

// ---------- Kernel 1: hw = h@W^T ; E=exp(si), F=exp(sj) ----------
// float4 LDS reads on BOTH operands (8 x b128 per 64 FMA -> VALU-bound)
__global__ __launch_bounds__(128) void GraphAttentionalLayer_1168231104632_kernel(
    const float* __restrict__ h,
    const float* __restrict__ WT,
    const float* __restrict__ a,
    float* __restrict__ hw,
    float* __restrict__ E,
    float* __restrict__ F)
{
    __shared__ float h_s[TI][HP];
    __shared__ float wt_s[32][HP];

    const int t = threadIdx.x;
    const int tx = t & 31, ty = t >> 5;
    const int b = blockIdx.x >> 7;
    const int i0 = (blockIdx.x & 127) * TI;
    const size_t base = ((size_t)b * NN + i0) * DD;

    for (int r = 0; r < TI; r++)
        h_s[r][t] = h[base + (size_t)r * DD + t];

    const int e0 = tx * 4, r0 = ty * 4;
    float acc[4][4];
#pragma unroll
    for (int i = 0; i < 4; i++)
#pragma unroll
        for (int j = 0; j < 4; j++) acc[i][j] = 0.f;

    for (int dc = 0; dc < DD; dc += 32) {
        __syncthreads();
        for (int rr = 0; rr < 32; rr++)
            wt_s[rr][t] = WT[(size_t)(dc + rr) * DD + t];
        __syncthreads();
#pragma unroll
        for (int dd = 0; dd < 32; dd += 4) {
            float wq[4][4], hq[4][4];
#pragma unroll
            for (int q = 0; q < 4; q++) {
                const float4 v = *reinterpret_cast<const float4*>(&wt_s[dd + q][e0]);
                wq[q][0] = v.x; wq[q][1] = v.y; wq[q][2] = v.z; wq[q][3] = v.w;
            }
#pragma unroll
            for (int r = 0; r < 4; r++) {
                const float4 v = *reinterpret_cast<const float4*>(&h_s[r0 + r][dc + dd]);
                hq[r][0] = v.x; hq[r][1] = v.y; hq[r][2] = v.z; hq[r][3] = v.w;
            }
#pragma unroll
            for (int r = 0; r < 4; r++)
#pragma unroll
                for (int q = 0; q < 4; q++) {
                    const float hv = hq[r][q];
#pragma unroll
                    for (int e = 0; e < 4; e++) acc[r][e] += hv * wq[q][e];
                }
        }
    }

#pragma unroll
    for (int r = 0; r < 4; r++) {
        float4 o = make_float4(acc[r][0], acc[r][1], acc[r][2], acc[r][3]);
        *reinterpret_cast<float4*>(&hw[base + (size_t)(r0 + r) * DD + e0]) = o;
    }

    const float4 aiv = *reinterpret_cast<const float4*>(&a[e0]);
    const float4 ajv = *reinterpret_cast<const float4*>(&a[DD + e0]);
    const float ai4[4] = {aiv.x, aiv.y, aiv.z, aiv.w};
    const float aj4[4] = {ajv.x, ajv.y, ajv.z, ajv.w};
#pragma unroll
    for (int r = 0; r < 4; r++) {
        float pi = 0.f, pj = 0.f;
#pragma unroll
        for (int e = 0; e < 4; e++) { pi += acc[r][e] * ai4[e]; pj += acc[r][e] * aj4[e]; }
#pragma unroll
        for (int off = 16; off > 0; off >>= 1) {
            pi += __shfl_down(pi, off, 32);
            pj += __shfl_down(pj, off, 32);
        }
        if (tx == 0) {
            const size_t row = (size_t)b * NN + i0 + r0 + r;
            E[row] = __expf(pi);
            F[row] = __expf(pj);
        }
    }
}

// ---------- Kernel 2: rank-sort, cooperative (verified r9) ----------
__global__ __launch_bounds__(256) void GraphAttentionalLayer_1168231104632_rank(
    const float* __restrict__ F,
    float* __restrict__ Fsorted,
    int* __restrict__ perm)
{
    __shared__ float F_s[NN];
    __shared__ int   part[4][64];

    const int t = threadIdx.x;
    const int b = blockIdx.x >> 5;
    const int j0 = (blockIdx.x & 31) * 64;
    const size_t nb = (size_t)b * NN;

    for (int q = 0; q < NN / 256; q++)
        F_s[q * 256 + t] = F[nb + q * 256 + t];
    __syncthreads();

    const int tj = t & 63, ts = t >> 6;
    const int j = j0 + tj;
    const float fj = F_s[j];
    const int m0 = ts * (NN / 4);
    int cnt = 0;
#pragma unroll 8
    for (int mi = 0; mi < NN / 4; mi++) {
        const int m = m0 + mi;
        const float fm = F_s[m];
        cnt += (fm < fj) | ((fm == fj) & (m < j));
    }
    part[ts][tj] = cnt;
    __syncthreads();
    if (ts == 0) {
        const int r = part[0][tj] + part[1][tj] + part[2][tj] + part[3][tj];
        Fsorted[nb + r] = fj;
        perm[nb + r] = j;
    }
}

// ---------- Kernel 3: chunked scans + F-prefix metadata ----------
__global__ __launch_bounds__(128) void GraphAttentionalLayer_1168231104632_scan(
    const float* __restrict__ hw,
    const float* __restrict__ Fsorted,
    const int* __restrict__ perm,
    float* __restrict__ Q0L, float* __restrict__ Q1L,
    float* __restrict__ C0,  float* __restrict__ C1,
    float* __restrict__ FPL, float* __restrict__ CF)
{
    const int t = threadIdx.x;
    const int b = blockIdx.x / NC, c = blockIdx.x % NC;
    const size_t nb = (size_t)b * NN;
    const int m0 = c * CH;

    int   jv[CH];
    float Fv[CH];
#pragma unroll
    for (int mm = 0; mm < CH; mm++) jv[mm] = perm[nb + m0 + mm];
#pragma unroll
    for (int mm = 0; mm < CH; mm++) Fv[mm] = Fsorted[nb + m0 + mm];

    float hv[CH];
#pragma unroll
    for (int mm = 0; mm < CH; mm++)
        hv[mm] = hw[(nb + jv[mm]) * DD + t];

    float a0 = 0.f, a1 = 0.f;
#pragma unroll
    for (int mm = 0; mm < CH; mm++) {
        const int m = m0 + mm;
        Q0L[(nb + m) * DD + t] = a0;
        Q1L[(nb + m) * DD + t] = a1;
        a0 += hv[mm];
        a1 += Fv[mm] * hv[mm];
    }
    C0[((size_t)b * NC + c) * DD + t] = a0;
    C1[((size_t)b * NC + c) * DD + t] = a1;

    if (t == 0) {
        float p = 0.f;
#pragma unroll
        for (int mm = 0; mm < CH; mm++) {
            FPL[nb + m0 + mm] = p;     // exclusive F-prefix within chunk
            p += Fv[mm];
        }
        CF[(size_t)b * NC + c] = p;    // chunk F total
    }
}

// ---------- Kernel 4: chunk-offset fixup + OF scan ----------
__global__ __launch_bounds__(128) void GraphAttentionalLayer_1168231104632_fix(
    const float* __restrict__ C0, const float* __restrict__ C1,
    const float* __restrict__ CF,
    float* __restrict__ O0, float* __restrict__ O1,
    float* __restrict__ OF)
{
    __shared__ float cf[NC], sc[NC];

    const int t = threadIdx.x;
    const int b = blockIdx.x;

    if (t < NC) { const float v = CF[(size_t)b * NC + t]; cf[t] = v; sc[t] = v; }
    __syncthreads();
    // Hillis-Steele inclusive scan of sc[0..63]
    for (int off = 1; off < NC; off <<= 1) {
        float v = 0.f;
        if (t < NC && t >= off) v = sc[t - off];
        __syncthreads();
        if (t < NC) sc[t] += v;
        __syncthreads();
    }
    if (t < NC) OF[(size_t)b * NO + t] = sc[t] - cf[t];   // exclusive
    if (t == 0) OF[(size_t)b * NO + NC] = sc[NC - 1];     // total F sum

    float o0 = 0.f, o1 = 0.f;
    for (int cc = 0; cc < NC; cc += 16) {
        float c0[16], c1[16];
#pragma unroll
        for (int q = 0; q < 16; q++) {
            c0[q] = C0[((size_t)b * NC + cc + q) * DD + t];
            c1[q] = C1[((size_t)b * NC + cc + q) * DD + t];
        }
#pragma unroll
        for (int q = 0; q < 16; q++) {
            O0[((size_t)b * NO + cc + q) * DD + t] = o0;
            O1[((size_t)b * NO + cc + q) * DD + t] = o1;
            o0 += c0[q];
            o1 += c1[q];
        }
    }
    O0[((size_t)b * NO + NC) * DD + t] = o0;   // grand totals
    O1[((size_t)b * NO + NC) * DD + t] = o1;
}

// ---------- Kernel 5: output, with fused k-search + z (one block per i-row) ----------
__global__ __launch_bounds__(128) void GraphAttentionalLayer_1168231104632_out(
    const float* __restrict__ Q0L, const float* __restrict__ Q1L,
    const float* __restrict__ O0,  const float* __restrict__ O1,
    const float* __restrict__ Fsorted, const float* __restrict__ FPL,
    const float* __restrict__ OF,  const float* __restrict__ E,
    float* __restrict__ out)
{
    __shared__ int   k_sh;
    __shared__ float e_sh, zi_sh;

    const int t = threadIdx.x;
    const int row = blockIdx.x;          // 0 .. BB*NN-1
    const int b = row >> 11;
    const size_t nb = (size_t)b * NN;

    if (t == 0) {
        const float Ei = E[row];
        const float thr = 1.0f / Ei;
        int lo = 0, hi = NN;
        while (lo < hi) {
            const int mid = (lo + hi) >> 1;
            if (Fsorted[nb + mid] < thr) lo = mid + 1; else hi = mid;
        }
        const float TF = OF[(size_t)b * NO + NC];
        const float Pk = (lo < NN) ? (OF[(size_t)b * NO + (lo >> 5)] + FPL[nb + lo]) : TF;
        const float z = Ei * (TF - Pk) + (float)lo;
        k_sh = lo; e_sh = Ei; zi_sh = 1.0f / z;
    }
    __syncthreads();

    const int k = k_sh;
    const float Ev = e_sh, zv = zi_sh;
    const float T1 = O1[((size_t)b * NO + NC) * DD + t];

    float num;
    if (k < NN) {
        const int c = k >> 5;
        const float q0 = Q0L[(nb + k) * DD + t] + O0[((size_t)b * NO + c) * DD + t];
        const float q1 = Q1L[(nb + k) * DD + t] + O1[((size_t)b * NO + c) * DD + t];
        num = Ev * (T1 - q1) + q0;
    } else {
        num = O0[((size_t)b * NO + NC) * DD + t];
    }
    out[(size_t)row * DD + t] = relu(num * zv);
}

extern "C" __attribute__((visibility("default")))
void kernel_launch(void* const* d_in, const int* in_sizes, int n_in,
                   void* d_out, int out_size, void* d_ws, size_t ws_size,
                   hipStream_t stream) {
    const float* h = nullptr; const float* W = nullptr; const float* a = nullptr;
    for (int i = 0; i < n_in; i++) {
        if (in_sizes[i] == BB * NN * DD)      h = (const float*)d_in[i];
        else if (in_sizes[i] == DD * DD)      W = (const float*)d_in[i];
        else if (in_sizes[i] == 2 * DD)       a = (const float*)d_in[i];
    }
    if (!h) h = (const float*)d_in[0];
    if (!W) W = (const float*)d_in[1];
    if (!a) a = (const float*)d_in[2];

    float* out = (float*)d_out;
    float* ws = (float*)d_ws;

    float* WT   = ws;                              // 16,384
    float* hw   = WT + DD * DD;                    // 2,097,152
    float* E    = hw + (size_t)BB * NN * DD;       // 16,384
    float* F    = E + BB * NN;                     // 16,384
    float* Fs   = F + BB * NN;                     // 16,384
    float* FPL  = Fs + BB * NN;                    // 16,384
    float* CF   = FPL + BB * NN;                   // 512
    float* OF   = CF + BB * NC;                    // 520
    int*   perm = (int*)(OF + BB * NO);            // 16,384
    float* Q0L  = (float*)(perm + BB * NN);        // 2,097,152
    float* Q1L  = Q0L + (size_t)BB * NN * DD;      // 2,097,152
    float* C0   = Q1L + (size_t)BB * NN * DD;      // 65,536
    float* C1   = C0 + BB * NC * DD;               // 65,536
    float* O0   = C1 + BB * NC * DD;               // 66,560
    float* O1   = O0 + BB * NO * DD;               // 66,560
    const size_t need = (size_t)((O1 + BB * NO * DD) - ws) * sizeof(float); // ~26.7 MB

    if (ws_size < need || d_ws == nullptr) {
        hipMemsetAsync(d_out, 0x42, (size_t)out_size * sizeof(float), stream);
        return;
    }

    GraphAttentionalLayer_1168231104632_tr<<<(DD * DD) / 256, 256, 0, stream>>>(W, WT);
    GraphAttentionalLayer_1168231104632_kernel<<<BB * (NN / TI), 128, 0, stream>>>(h, WT, a, hw, E, F);
    GraphAttentionalLayer_1168231104632_rank<<<BB * 32, 256, 0, stream>>>(F, Fs, perm);
    GraphAttentionalLayer_1168231104632_scan<<<BB * NC, 128, 0, stream>>>(hw, Fs, perm, Q0L, Q1L, C0, C1, FPL, CF);
    GraphAttentionalLayer_1168231104632_fix<<<BB, 128, 0, stream>>>(C0, C1, CF, O0, O1, OF);
    GraphAttentionalLayer_1168231104632_out<<<BB * NN, 128, 0, stream>>>(Q0L, Q1L, O0, O1, Fs, FPL, OF, E, out);
}